// Round 7
// baseline (296.222 us; speedup 1.0000x reference)
//
#include <hip/hip_runtime.h>
#include <hip/hip_bf16.h>

#define EPS 1e-3f

typedef __attribute__((ext_vector_type(8))) short short8;
typedef __attribute__((ext_vector_type(4))) float v4f;

__device__ __forceinline__ unsigned short f2bf(float f) {
    unsigned int u = __float_as_uint(f);
    unsigned int r = (u + 0x7fffu + ((u >> 16) & 1u)) >> 16;
    return (unsigned short)r;
}

// ---------------------------------------------------------------------------
// Prep: fold biases + BN into per-channel affine; transpose pw_kernel into
// bf16 MFMA B-fragment layout.  (unchanged)
// ---------------------------------------------------------------------------
__global__ __launch_bounds__(256) void prep_kernel(
    const float* __restrict__ dwb,
    const float* __restrict__ g1, const float* __restrict__ b1,
    const float* __restrict__ m1, const float* __restrict__ v1,
    const float* __restrict__ pw, const float* __restrict__ pwb,
    const float* __restrict__ g2, const float* __restrict__ b2,
    const float* __restrict__ m2, const float* __restrict__ v2,
    float* __restrict__ scale1, float* __restrict__ shift1,
    float* __restrict__ s2, float* __restrict__ t2,
    unsigned short* __restrict__ Wt)
{
    int tid = threadIdx.x;
    if (blockIdx.x == 0) {
        if (tid < 64) {
            float inv = g1[tid] * rsqrtf(v1[tid] + EPS);
            scale1[tid] = inv;
            shift1[tid] = dwb[tid] * inv + b1[tid] - m1[tid] * inv;
        }
        if (tid < 128) {
            float inv = g2[tid] * rsqrtf(v2[tid] + EPS);
            s2[tid] = inv;
            t2[tid] = pwb[tid] * inv + b2[tid] - m2[tid] * inv;
        }
    }
    int idx = blockIdx.x * 256 + tid;      // 0..8191
    int j     = idx & 7;
    int lane  = (idx >> 3) & 63;
    int kstep = (idx >> 9) & 1;
    int ntile = idx >> 10;                 // 0..7
    int k = kstep * 32 + (lane >> 4) * 8 + j;
    int f = ntile * 16 + (lane & 15);
    Wt[idx] = f2bf(pw[k * 128 + f]);
}

// ---------------------------------------------------------------------------
// Fused kernel, occupancy-first v2.
// R6 post-mortem: WRITE=output exactly (no spill), but Occupancy stuck ~18%
// because grid 576 = only 2.25 blocks/CU -- the grid, not LDS/VGPR, was the
// cap.  This version: DPB=3 -> grid 1152 (4.5 blocks/CU, ~18 waves/CU);
// yS double-buffered -> ONE barrier per finish-iter; launch_bounds(256,5)
// (VGPR cap 102, current use 84) so residency is grid-limited only.
// Conv still loads x directly from global (clamped + edge masks, private).
// LDS = 27.4 KB (weights + yS[2]).
// ---------------------------------------------------------------------------
__global__ __launch_bounds__(256, 5) void fused_kernel(
    const float* __restrict__ x,
    const float* __restrict__ wgt,          // (3,3,3,1,64)
    const float* __restrict__ scale1,
    const float* __restrict__ shift1,
    const unsigned short* __restrict__ Wt,  // bf16 B-fragments (16 KB)
    const float* __restrict__ s2,
    const float* __restrict__ t2,
    float* __restrict__ out)
{
    __shared__ float wS[27 * 64];              // 6912 B
    __shared__ float sS[64];
    __shared__ float tS[64];
    __shared__ float s2S[128];
    __shared__ float t2S[128];
    __shared__ unsigned short yS[2][64 * 72];  // 2 x 9216 B

    int tid = threadIdx.x;
    for (int i = tid; i < 27 * 64; i += 256) wS[i] = wgt[i];
    if (tid < 64) { sS[tid] = scale1[tid]; tS[tid] = shift1[tid]; }
    if (tid < 128) { s2S[tid] = s2[tid]; t2S[tid] = t2[tid]; }
    __syncthreads();

    // XCD-aware decode: 1152 blocks = 8 xcd * 144; each XCD owns 4
    // consecutive bdg groups (contiguous 12-deep d range -> L2-shared halos)
    int n   = blockIdx.x;
    int g   = (n & 7) * 144 + (n >> 3);
    int bdg = g / 36;              // 0..31 = b*16 + dgrp
    int hw  = g % 36;
    int b    = bdg >> 4;
    int dgrp = bdg & 15;
    int d0   = dgrp * 3;
    int w0  = (hw % 3) * 16;
    int h0  = (hw / 3) * 4;

    int tx = tid & 15;            // channel group
    int ty = tid >> 4;            // 0..15
    int c0 = tx * 4;
    int wq = ty & 3;
    int rh = ty >> 2;             // == wave id -> h is wave-uniform

    int wv   = tid >> 6;
    int lane = tid & 63;
    int lrow = lane & 15;
    int quad = lane >> 4;

    // ---- per-thread invariant conv addressing (clamped) ----
    int w0t = w0 + wq * 4;
    float mwL = (w0t >= 1)  ? 1.f : 0.f;   // window p=0 (zw = w0t-1)
    float mwR = (w0t <= 43) ? 1.f : 0.f;   // window p=5 (zw = w0t+4)
    int wcl[6];
    #pragma unroll
    for (int p = 0; p < 6; ++p)
        wcl[p] = min(max(w0t - 1 + p, 0), 47) * 64;

    int h = h0 + rh;
    bool hok[3];
    int  hcl[3];
    #pragma unroll
    for (int hh = 0; hh < 3; ++hh) {
        int zh = h + hh - 1;
        hok[hh] = (zh >= 0 && zh < 48);
        hcl[hh] = min(max(zh, 0), 47) * 48 * 64;
    }

    // 3 accumulator sets, aid == m (no rotation at DPB=3)
    float4 acc[3][4];
    #pragma unroll
    for (int a = 0; a < 3; ++a)
        #pragma unroll
        for (int r = 0; r < 4; ++r) acc[a][r] = make_float4(0.f, 0.f, 0.f, 0.f);

    #pragma unroll
    for (int k = 0; k < 5; ++k) {
        int s = d0 - 1 + k;                    // slab depth
        bool s_ok = (s >= 0) && (s < 48);      // block-uniform

        // ---- conv: direct global loads (private, no barriers) ----
        if (s_ok) {
            const float* dp = x + ((long)(b * 48 + s) * 48 * 48) * 64 + c0;
            #pragma unroll
            for (int hh = 0; hh < 3; ++hh) {
                if (hok[hh]) {                 // wave-uniform branch
                    const float* rowp = dp + hcl[hh];
                    float4 xv[6];
                    #pragma unroll
                    for (int p = 0; p < 6; ++p)
                        xv[p] = *(const float4*)(rowp + wcl[p]);
                    xv[0].x *= mwL; xv[0].y *= mwL; xv[0].z *= mwL; xv[0].w *= mwL;
                    xv[5].x *= mwR; xv[5].y *= mwR; xv[5].z *= mwR; xv[5].w *= mwR;
                    #pragma unroll
                    for (int m = 0; m < 3; ++m) {
                        if (m >= k - 2 && m <= k) {      // folds at compile time
                            const int wz = k - m;        // weight z-tap
                            #pragma unroll
                            for (int ww = 0; ww < 3; ++ww) {
                                const float4 wvv = *(const float4*)(&wS[((wz * 3 + hh) * 3 + ww) * 64 + c0]);
                                #pragma unroll
                                for (int r = 0; r < 4; ++r) {
                                    acc[m][r].x += xv[r + ww].x * wvv.x;
                                    acc[m][r].y += xv[r + ww].y * wvv.y;
                                    acc[m][r].z += xv[r + ww].z * wvv.z;
                                    acc[m][r].w += xv[r + ww].w * wvv.w;
                                }
                            }
                        }
                    }
                }
            }
        }

        // ---- finish output m = k-2 (m = 0,1,2 at k = 2,3,4) ----
        if (k >= 2) {
            const int m = k - 2;
            const int bu = m & 1;              // yS buffer

            // BN1 + ReLU + bf16 -> yS[bu]
            {
                float4 s1 = *(const float4*)(&sS[c0]);
                float4 t1 = *(const float4*)(&tS[c0]);
                #pragma unroll
                for (int r = 0; r < 4; ++r) {
                    ushort4 o;
                    o.x = f2bf(fmaxf(acc[m][r].x * s1.x + t1.x, 0.f));
                    o.y = f2bf(fmaxf(acc[m][r].y * s1.y + t1.y, 0.f));
                    o.z = f2bf(fmaxf(acc[m][r].z * s1.z + t1.z, 0.f));
                    o.w = f2bf(fmaxf(acc[m][r].w * s1.w + t1.w, 0.f));
                    *(ushort4*)(&yS[bu][(ty * 4 + r) * 72 + c0]) = o;
                }
            }
            __syncthreads();   // RAW: yS[bu] visible.  (WAR across buffers is
                               // fenced by the NEXT iteration's barrier.)

            // GEMM: 4 waves, wave = 16 rows x 128 cols, K=64, 2 MFMA k-steps
            const short8 a0 = *(const short8*)(&yS[bu][(wv * 16 + lrow) * 72 + quad * 8]);
            const short8 a1 = *(const short8*)(&yS[bu][(wv * 16 + lrow) * 72 + 32 + quad * 8]);

            v4f gacc[8];
            #pragma unroll
            for (int nn = 0; nn < 8; ++nn) gacc[nn] = (v4f){0.f, 0.f, 0.f, 0.f};

            #pragma unroll
            for (int nn = 0; nn < 8; ++nn) {
                short8 b0 = *(const short8*)(Wt + ((nn * 2 + 0) * 64 + lane) * 8);
                short8 b1 = *(const short8*)(Wt + ((nn * 2 + 1) * 64 + lane) * 8);
                gacc[nn] = __builtin_amdgcn_mfma_f32_16x16x32_bf16(a0, b0, gacc[nn], 0, 0, 0);
                gacc[nn] = __builtin_amdgcn_mfma_f32_16x16x32_bf16(a1, b1, gacc[nn], 0, 0, 0);
            }

            // BN2 + ReLU epilogue. D: col=lane&15, row=quad*4+reg.
            int d = d0 + m;
            long base_out = ((((long)b * 48 + d) * 48 + (h0 + wv)) * 48 + w0) * 128;
            #pragma unroll
            for (int nn = 0; nn < 8; ++nn) {
                int f = nn * 16 + lrow;
                float sf = s2S[f];
                float tf = t2S[f];
                #pragma unroll
                for (int r = 0; r < 4; ++r) {
                    float v = fmaxf(gacc[nn][r] * sf + tf, 0.f);
                    out[base_out + (quad * 4 + r) * 128 + f] = v;
                }
            }
        }
    }
}

// ---------------------------------------------------------------------------
extern "C" void kernel_launch(void* const* d_in, const int* in_sizes, int n_in,
                              void* d_out, int out_size, void* d_ws, size_t ws_size,
                              hipStream_t stream)
{
    const float* x   = (const float*)d_in[0];
    const float* dwk = (const float*)d_in[1];
    const float* dwb = (const float*)d_in[2];
    const float* g1  = (const float*)d_in[3];
    const float* b1  = (const float*)d_in[4];
    const float* m1  = (const float*)d_in[5];
    const float* v1  = (const float*)d_in[6];
    const float* pw  = (const float*)d_in[7];
    const float* pwb = (const float*)d_in[8];
    const float* g2  = (const float*)d_in[9];
    const float* b2  = (const float*)d_in[10];
    const float* m2  = (const float*)d_in[11];
    const float* v2  = (const float*)d_in[12];

    float* outp = (float*)d_out;

    float* scale1 = (float*)d_ws;
    float* shift1 = scale1 + 64;
    float* s2     = scale1 + 128;
    float* t2     = scale1 + 256;
    unsigned short* Wt = (unsigned short*)((char*)d_ws + 2048);

    hipLaunchKernelGGL(prep_kernel, dim3(32), dim3(256), 0, stream,
                       dwb, g1, b1, m1, v1, pw, pwb, g2, b2, m2, v2,
                       scale1, shift1, s2, t2, Wt);

    hipLaunchKernelGGL(fused_kernel, dim3(1152), dim3(256), 0, stream,
                       x, dwk, scale1, shift1, Wt, s2, t2, outp);
}

// Round 8
// 242.204 us; speedup vs baseline: 1.2230x; 1.2230x over previous
//
#include <hip/hip_runtime.h>
#include <hip/hip_bf16.h>

#define EPS 1e-3f

typedef __attribute__((ext_vector_type(8))) short short8;
typedef __attribute__((ext_vector_type(4))) float v4f;

__device__ __forceinline__ unsigned short f2bf(float f) {
    unsigned int u = __float_as_uint(f);
    unsigned int r = (u + 0x7fffu + ((u >> 16) & 1u)) >> 16;
    return (unsigned short)r;
}

// ---------------------------------------------------------------------------
// Prep: fold biases + BN into per-channel affine; transpose pw_kernel into
// bf16 MFMA B-fragment layout.  (unchanged)
// ---------------------------------------------------------------------------
__global__ __launch_bounds__(256) void prep_kernel(
    const float* __restrict__ dwb,
    const float* __restrict__ g1, const float* __restrict__ b1,
    const float* __restrict__ m1, const float* __restrict__ v1,
    const float* __restrict__ pw, const float* __restrict__ pwb,
    const float* __restrict__ g2, const float* __restrict__ b2,
    const float* __restrict__ m2, const float* __restrict__ v2,
    float* __restrict__ scale1, float* __restrict__ shift1,
    float* __restrict__ s2, float* __restrict__ t2,
    unsigned short* __restrict__ Wt)
{
    int tid = threadIdx.x;
    if (blockIdx.x == 0) {
        if (tid < 64) {
            float inv = g1[tid] * rsqrtf(v1[tid] + EPS);
            scale1[tid] = inv;
            shift1[tid] = dwb[tid] * inv + b1[tid] - m1[tid] * inv;
        }
        if (tid < 128) {
            float inv = g2[tid] * rsqrtf(v2[tid] + EPS);
            s2[tid] = inv;
            t2[tid] = pwb[tid] * inv + b2[tid] - m2[tid] * inv;
        }
    }
    int idx = blockIdx.x * 256 + tid;      // 0..8191
    int j     = idx & 7;
    int lane  = (idx >> 3) & 63;
    int kstep = (idx >> 9) & 1;
    int ntile = idx >> 10;                 // 0..7
    int k = kstep * 32 + (lane >> 4) * 8 + j;
    int f = ntile * 16 + (lane & 15);
    Wt[idx] = f2bf(pw[k * 128 + f]);
}

// ---------------------------------------------------------------------------
// Fused kernel, occupancy-first v3.
// R7 post-mortem: grid 1152 DID lift occupancy 18->42% (theory confirmed),
// but __launch_bounds__(256,5) capped VGPR at ~96 and the allocator squeezed
// to 48 -> acc[3][4]+xv spilled to scratch (WRITE 363 MB, FETCH 220 MB).
// Rule learned: this kernel's natural register set is ~90 VGPR; never cap
// below ~128.  Single change vs R7: launch_bounds (256,5) -> (256,4)
// (VGPR cap 128, no spill; residency 4.5 blocks/CU grid-limited).
// Structure: DPB=3, grid 1152, conv direct-from-global (clamped + masks),
// yS double-buffered, ONE barrier per finish-iter.  LDS 27.1 KB.
// ---------------------------------------------------------------------------
__global__ __launch_bounds__(256, 4) void fused_kernel(
    const float* __restrict__ x,
    const float* __restrict__ wgt,          // (3,3,3,1,64)
    const float* __restrict__ scale1,
    const float* __restrict__ shift1,
    const unsigned short* __restrict__ Wt,  // bf16 B-fragments (16 KB)
    const float* __restrict__ s2,
    const float* __restrict__ t2,
    float* __restrict__ out)
{
    __shared__ float wS[27 * 64];              // 6912 B
    __shared__ float sS[64];
    __shared__ float tS[64];
    __shared__ float s2S[128];
    __shared__ float t2S[128];
    __shared__ unsigned short yS[2][64 * 72];  // 2 x 9216 B

    int tid = threadIdx.x;
    for (int i = tid; i < 27 * 64; i += 256) wS[i] = wgt[i];
    if (tid < 64) { sS[tid] = scale1[tid]; tS[tid] = shift1[tid]; }
    if (tid < 128) { s2S[tid] = s2[tid]; t2S[tid] = t2[tid]; }
    __syncthreads();

    // XCD-aware decode: 1152 blocks = 8 xcd * 144; each XCD owns 4
    // consecutive bdg groups (contiguous 12-deep d range -> L2-shared halos)
    int n   = blockIdx.x;
    int g   = (n & 7) * 144 + (n >> 3);
    int bdg = g / 36;              // 0..31 = b*16 + dgrp
    int hw  = g % 36;
    int b    = bdg >> 4;
    int dgrp = bdg & 15;
    int d0   = dgrp * 3;
    int w0  = (hw % 3) * 16;
    int h0  = (hw / 3) * 4;

    int tx = tid & 15;            // channel group
    int ty = tid >> 4;            // 0..15
    int c0 = tx * 4;
    int wq = ty & 3;
    int rh = ty >> 2;             // == wave id -> h is wave-uniform

    int wv   = tid >> 6;
    int lane = tid & 63;
    int lrow = lane & 15;
    int quad = lane >> 4;

    // ---- per-thread invariant conv addressing (clamped) ----
    int w0t = w0 + wq * 4;
    float mwL = (w0t >= 1)  ? 1.f : 0.f;   // window p=0 (zw = w0t-1)
    float mwR = (w0t <= 43) ? 1.f : 0.f;   // window p=5 (zw = w0t+4)
    int wcl[6];
    #pragma unroll
    for (int p = 0; p < 6; ++p)
        wcl[p] = min(max(w0t - 1 + p, 0), 47) * 64;

    int h = h0 + rh;
    bool hok[3];
    int  hcl[3];
    #pragma unroll
    for (int hh = 0; hh < 3; ++hh) {
        int zh = h + hh - 1;
        hok[hh] = (zh >= 0 && zh < 48);
        hcl[hh] = min(max(zh, 0), 47) * 48 * 64;
    }

    // 3 accumulator sets, aid == m (no rotation at DPB=3)
    float4 acc[3][4];
    #pragma unroll
    for (int a = 0; a < 3; ++a)
        #pragma unroll
        for (int r = 0; r < 4; ++r) acc[a][r] = make_float4(0.f, 0.f, 0.f, 0.f);

    #pragma unroll
    for (int k = 0; k < 5; ++k) {
        int s = d0 - 1 + k;                    // slab depth
        bool s_ok = (s >= 0) && (s < 48);      // block-uniform

        // ---- conv: direct global loads (private, no barriers) ----
        if (s_ok) {
            const float* dp = x + ((long)(b * 48 + s) * 48 * 48) * 64 + c0;
            #pragma unroll
            for (int hh = 0; hh < 3; ++hh) {
                if (hok[hh]) {                 // wave-uniform branch
                    const float* rowp = dp + hcl[hh];
                    float4 xv[6];
                    #pragma unroll
                    for (int p = 0; p < 6; ++p)
                        xv[p] = *(const float4*)(rowp + wcl[p]);
                    xv[0].x *= mwL; xv[0].y *= mwL; xv[0].z *= mwL; xv[0].w *= mwL;
                    xv[5].x *= mwR; xv[5].y *= mwR; xv[5].z *= mwR; xv[5].w *= mwR;
                    #pragma unroll
                    for (int m = 0; m < 3; ++m) {
                        if (m >= k - 2 && m <= k) {      // folds at compile time
                            const int wz = k - m;        // weight z-tap
                            #pragma unroll
                            for (int ww = 0; ww < 3; ++ww) {
                                const float4 wvv = *(const float4*)(&wS[((wz * 3 + hh) * 3 + ww) * 64 + c0]);
                                #pragma unroll
                                for (int r = 0; r < 4; ++r) {
                                    acc[m][r].x += xv[r + ww].x * wvv.x;
                                    acc[m][r].y += xv[r + ww].y * wvv.y;
                                    acc[m][r].z += xv[r + ww].z * wvv.z;
                                    acc[m][r].w += xv[r + ww].w * wvv.w;
                                }
                            }
                        }
                    }
                }
            }
        }

        // ---- finish output m = k-2 (m = 0,1,2 at k = 2,3,4) ----
        if (k >= 2) {
            const int m = k - 2;
            const int bu = m & 1;              // yS buffer

            // BN1 + ReLU + bf16 -> yS[bu]
            {
                float4 s1 = *(const float4*)(&sS[c0]);
                float4 t1 = *(const float4*)(&tS[c0]);
                #pragma unroll
                for (int r = 0; r < 4; ++r) {
                    ushort4 o;
                    o.x = f2bf(fmaxf(acc[m][r].x * s1.x + t1.x, 0.f));
                    o.y = f2bf(fmaxf(acc[m][r].y * s1.y + t1.y, 0.f));
                    o.z = f2bf(fmaxf(acc[m][r].z * s1.z + t1.z, 0.f));
                    o.w = f2bf(fmaxf(acc[m][r].w * s1.w + t1.w, 0.f));
                    *(ushort4*)(&yS[bu][(ty * 4 + r) * 72 + c0]) = o;
                }
            }
            __syncthreads();   // RAW: yS[bu] visible.  (WAR across buffers is
                               // fenced by the NEXT iteration's barrier.)

            // GEMM: 4 waves, wave = 16 rows x 128 cols, K=64, 2 MFMA k-steps
            const short8 a0 = *(const short8*)(&yS[bu][(wv * 16 + lrow) * 72 + quad * 8]);
            const short8 a1 = *(const short8*)(&yS[bu][(wv * 16 + lrow) * 72 + 32 + quad * 8]);

            v4f gacc[8];
            #pragma unroll
            for (int nn = 0; nn < 8; ++nn) gacc[nn] = (v4f){0.f, 0.f, 0.f, 0.f};

            #pragma unroll
            for (int nn = 0; nn < 8; ++nn) {
                short8 b0 = *(const short8*)(Wt + ((nn * 2 + 0) * 64 + lane) * 8);
                short8 b1 = *(const short8*)(Wt + ((nn * 2 + 1) * 64 + lane) * 8);
                gacc[nn] = __builtin_amdgcn_mfma_f32_16x16x32_bf16(a0, b0, gacc[nn], 0, 0, 0);
                gacc[nn] = __builtin_amdgcn_mfma_f32_16x16x32_bf16(a1, b1, gacc[nn], 0, 0, 0);
            }

            // BN2 + ReLU epilogue. D: col=lane&15, row=quad*4+reg.
            int d = d0 + m;
            long base_out = ((((long)b * 48 + d) * 48 + (h0 + wv)) * 48 + w0) * 128;
            #pragma unroll
            for (int nn = 0; nn < 8; ++nn) {
                int f = nn * 16 + lrow;
                float sf = s2S[f];
                float tf = t2S[f];
                #pragma unroll
                for (int r = 0; r < 4; ++r) {
                    float v = fmaxf(gacc[nn][r] * sf + tf, 0.f);
                    out[base_out + (quad * 4 + r) * 128 + f] = v;
                }
            }
        }
    }
}

// ---------------------------------------------------------------------------
extern "C" void kernel_launch(void* const* d_in, const int* in_sizes, int n_in,
                              void* d_out, int out_size, void* d_ws, size_t ws_size,
                              hipStream_t stream)
{
    const float* x   = (const float*)d_in[0];
    const float* dwk = (const float*)d_in[1];
    const float* dwb = (const float*)d_in[2];
    const float* g1  = (const float*)d_in[3];
    const float* b1  = (const float*)d_in[4];
    const float* m1  = (const float*)d_in[5];
    const float* v1  = (const float*)d_in[6];
    const float* pw  = (const float*)d_in[7];
    const float* pwb = (const float*)d_in[8];
    const float* g2  = (const float*)d_in[9];
    const float* b2  = (const float*)d_in[10];
    const float* m2  = (const float*)d_in[11];
    const float* v2  = (const float*)d_in[12];

    float* outp = (float*)d_out;

    float* scale1 = (float*)d_ws;
    float* shift1 = scale1 + 64;
    float* s2     = scale1 + 128;
    float* t2     = scale1 + 256;
    unsigned short* Wt = (unsigned short*)((char*)d_ws + 2048);

    hipLaunchKernelGGL(prep_kernel, dim3(32), dim3(256), 0, stream,
                       dwb, g1, b1, m1, v1, pw, pwb, g2, b2, m2, v2,
                       scale1, shift1, s2, t2, Wt);

    hipLaunchKernelGGL(fused_kernel, dim3(1152), dim3(256), 0, stream,
                       x, dwk, scale1, shift1, Wt, s2, t2, outp);
}

// Round 9
// 206.515 us; speedup vs baseline: 1.4344x; 1.1728x over previous
//
#include <hip/hip_runtime.h>
#include <hip/hip_bf16.h>

#define EPS 1e-3f

typedef __attribute__((ext_vector_type(8))) short short8;
typedef __attribute__((ext_vector_type(4))) float v4f;

__device__ __forceinline__ unsigned short f2bf(float f) {
    unsigned int u = __float_as_uint(f);
    unsigned int r = (u + 0x7fffu + ((u >> 16) & 1u)) >> 16;
    return (unsigned short)r;
}

// ---------------------------------------------------------------------------
// Prep: fold biases + BN into per-channel affine; transpose pw_kernel into
// bf16 MFMA B-fragment layout.  (unchanged)
// ---------------------------------------------------------------------------
__global__ __launch_bounds__(256) void prep_kernel(
    const float* __restrict__ dwb,
    const float* __restrict__ g1, const float* __restrict__ b1,
    const float* __restrict__ m1, const float* __restrict__ v1,
    const float* __restrict__ pw, const float* __restrict__ pwb,
    const float* __restrict__ g2, const float* __restrict__ b2,
    const float* __restrict__ m2, const float* __restrict__ v2,
    float* __restrict__ scale1, float* __restrict__ shift1,
    float* __restrict__ s2, float* __restrict__ t2,
    unsigned short* __restrict__ Wt)
{
    int tid = threadIdx.x;
    if (blockIdx.x == 0) {
        if (tid < 64) {
            float inv = g1[tid] * rsqrtf(v1[tid] + EPS);
            scale1[tid] = inv;
            shift1[tid] = dwb[tid] * inv + b1[tid] - m1[tid] * inv;
        }
        if (tid < 128) {
            float inv = g2[tid] * rsqrtf(v2[tid] + EPS);
            s2[tid] = inv;
            t2[tid] = pwb[tid] * inv + b2[tid] - m2[tid] * inv;
        }
    }
    int idx = blockIdx.x * 256 + tid;      // 0..8191
    int j     = idx & 7;
    int lane  = (idx >> 3) & 63;
    int kstep = (idx >> 9) & 1;
    int ntile = idx >> 10;                 // 0..7
    int k = kstep * 32 + (lane >> 4) * 8 + j;
    int f = ntile * 16 + (lane & 15);
    Wt[idx] = f2bf(pw[k * 128 + f]);
}

// ---------------------------------------------------------------------------
// Fused kernel, occupancy-first v4.
// R8 post-mortem: launch_bounds min-waves hint empirically maps to
// (256,3)->84 VGPR no spill / (256,4)->64+spill / (256,5)->48+heavy spill.
// The allocator squeezes below the documented cap, so the ONLY proven
// no-spill setting is (256,3).  Single change vs R8: (256,4) -> (256,3).
// At natural ~84 VGPR: RF allows 6 blocks/CU, LDS 5, grid asks 4.5 ->
// grid-limited residency with zero scratch traffic.
// Structure: DPB=3, grid 1152, conv direct-from-global (clamped + masks),
// yS double-buffered, ONE barrier per finish-iter.  LDS 27.1 KB.
// ---------------------------------------------------------------------------
__global__ __launch_bounds__(256, 3) void fused_kernel(
    const float* __restrict__ x,
    const float* __restrict__ wgt,          // (3,3,3,1,64)
    const float* __restrict__ scale1,
    const float* __restrict__ shift1,
    const unsigned short* __restrict__ Wt,  // bf16 B-fragments (16 KB)
    const float* __restrict__ s2,
    const float* __restrict__ t2,
    float* __restrict__ out)
{
    __shared__ float wS[27 * 64];              // 6912 B
    __shared__ float sS[64];
    __shared__ float tS[64];
    __shared__ float s2S[128];
    __shared__ float t2S[128];
    __shared__ unsigned short yS[2][64 * 72];  // 2 x 9216 B

    int tid = threadIdx.x;
    for (int i = tid; i < 27 * 64; i += 256) wS[i] = wgt[i];
    if (tid < 64) { sS[tid] = scale1[tid]; tS[tid] = shift1[tid]; }
    if (tid < 128) { s2S[tid] = s2[tid]; t2S[tid] = t2[tid]; }
    __syncthreads();

    // XCD-aware decode: 1152 blocks = 8 xcd * 144; each XCD owns 4
    // consecutive bdg groups (contiguous 12-deep d range -> L2-shared halos)
    int n   = blockIdx.x;
    int g   = (n & 7) * 144 + (n >> 3);
    int bdg = g / 36;              // 0..31 = b*16 + dgrp
    int hw  = g % 36;
    int b    = bdg >> 4;
    int dgrp = bdg & 15;
    int d0   = dgrp * 3;
    int w0  = (hw % 3) * 16;
    int h0  = (hw / 3) * 4;

    int tx = tid & 15;            // channel group
    int ty = tid >> 4;            // 0..15
    int c0 = tx * 4;
    int wq = ty & 3;
    int rh = ty >> 2;             // == wave id -> h is wave-uniform

    int wv   = tid >> 6;
    int lane = tid & 63;
    int lrow = lane & 15;
    int quad = lane >> 4;

    // ---- per-thread invariant conv addressing (clamped) ----
    int w0t = w0 + wq * 4;
    float mwL = (w0t >= 1)  ? 1.f : 0.f;   // window p=0 (zw = w0t-1)
    float mwR = (w0t <= 43) ? 1.f : 0.f;   // window p=5 (zw = w0t+4)
    int wcl[6];
    #pragma unroll
    for (int p = 0; p < 6; ++p)
        wcl[p] = min(max(w0t - 1 + p, 0), 47) * 64;

    int h = h0 + rh;
    bool hok[3];
    int  hcl[3];
    #pragma unroll
    for (int hh = 0; hh < 3; ++hh) {
        int zh = h + hh - 1;
        hok[hh] = (zh >= 0 && zh < 48);
        hcl[hh] = min(max(zh, 0), 47) * 48 * 64;
    }

    // 3 accumulator sets, aid == m (no rotation at DPB=3)
    float4 acc[3][4];
    #pragma unroll
    for (int a = 0; a < 3; ++a)
        #pragma unroll
        for (int r = 0; r < 4; ++r) acc[a][r] = make_float4(0.f, 0.f, 0.f, 0.f);

    #pragma unroll
    for (int k = 0; k < 5; ++k) {
        int s = d0 - 1 + k;                    // slab depth
        bool s_ok = (s >= 0) && (s < 48);      // block-uniform

        // ---- conv: direct global loads (private, no barriers) ----
        if (s_ok) {
            const float* dp = x + ((long)(b * 48 + s) * 48 * 48) * 64 + c0;
            #pragma unroll
            for (int hh = 0; hh < 3; ++hh) {
                if (hok[hh]) {                 // wave-uniform branch
                    const float* rowp = dp + hcl[hh];
                    float4 xv[6];
                    #pragma unroll
                    for (int p = 0; p < 6; ++p)
                        xv[p] = *(const float4*)(rowp + wcl[p]);
                    xv[0].x *= mwL; xv[0].y *= mwL; xv[0].z *= mwL; xv[0].w *= mwL;
                    xv[5].x *= mwR; xv[5].y *= mwR; xv[5].z *= mwR; xv[5].w *= mwR;
                    #pragma unroll
                    for (int m = 0; m < 3; ++m) {
                        if (m >= k - 2 && m <= k) {      // folds at compile time
                            const int wz = k - m;        // weight z-tap
                            #pragma unroll
                            for (int ww = 0; ww < 3; ++ww) {
                                const float4 wvv = *(const float4*)(&wS[((wz * 3 + hh) * 3 + ww) * 64 + c0]);
                                #pragma unroll
                                for (int r = 0; r < 4; ++r) {
                                    acc[m][r].x += xv[r + ww].x * wvv.x;
                                    acc[m][r].y += xv[r + ww].y * wvv.y;
                                    acc[m][r].z += xv[r + ww].z * wvv.z;
                                    acc[m][r].w += xv[r + ww].w * wvv.w;
                                }
                            }
                        }
                    }
                }
            }
        }

        // ---- finish output m = k-2 (m = 0,1,2 at k = 2,3,4) ----
        if (k >= 2) {
            const int m = k - 2;
            const int bu = m & 1;              // yS buffer

            // BN1 + ReLU + bf16 -> yS[bu]
            {
                float4 s1 = *(const float4*)(&sS[c0]);
                float4 t1 = *(const float4*)(&tS[c0]);
                #pragma unroll
                for (int r = 0; r < 4; ++r) {
                    ushort4 o;
                    o.x = f2bf(fmaxf(acc[m][r].x * s1.x + t1.x, 0.f));
                    o.y = f2bf(fmaxf(acc[m][r].y * s1.y + t1.y, 0.f));
                    o.z = f2bf(fmaxf(acc[m][r].z * s1.z + t1.z, 0.f));
                    o.w = f2bf(fmaxf(acc[m][r].w * s1.w + t1.w, 0.f));
                    *(ushort4*)(&yS[bu][(ty * 4 + r) * 72 + c0]) = o;
                }
            }
            __syncthreads();   // RAW: yS[bu] visible.  (WAR across buffers is
                               // fenced by the NEXT iteration's barrier.)

            // GEMM: 4 waves, wave = 16 rows x 128 cols, K=64, 2 MFMA k-steps
            const short8 a0 = *(const short8*)(&yS[bu][(wv * 16 + lrow) * 72 + quad * 8]);
            const short8 a1 = *(const short8*)(&yS[bu][(wv * 16 + lrow) * 72 + 32 + quad * 8]);

            v4f gacc[8];
            #pragma unroll
            for (int nn = 0; nn < 8; ++nn) gacc[nn] = (v4f){0.f, 0.f, 0.f, 0.f};

            #pragma unroll
            for (int nn = 0; nn < 8; ++nn) {
                short8 b0 = *(const short8*)(Wt + ((nn * 2 + 0) * 64 + lane) * 8);
                short8 b1 = *(const short8*)(Wt + ((nn * 2 + 1) * 64 + lane) * 8);
                gacc[nn] = __builtin_amdgcn_mfma_f32_16x16x32_bf16(a0, b0, gacc[nn], 0, 0, 0);
                gacc[nn] = __builtin_amdgcn_mfma_f32_16x16x32_bf16(a1, b1, gacc[nn], 0, 0, 0);
            }

            // BN2 + ReLU epilogue. D: col=lane&15, row=quad*4+reg.
            int d = d0 + m;
            long base_out = ((((long)b * 48 + d) * 48 + (h0 + wv)) * 48 + w0) * 128;
            #pragma unroll
            for (int nn = 0; nn < 8; ++nn) {
                int f = nn * 16 + lrow;
                float sf = s2S[f];
                float tf = t2S[f];
                #pragma unroll
                for (int r = 0; r < 4; ++r) {
                    float v = fmaxf(gacc[nn][r] * sf + tf, 0.f);
                    out[base_out + (quad * 4 + r) * 128 + f] = v;
                }
            }
        }
    }
}

// ---------------------------------------------------------------------------
extern "C" void kernel_launch(void* const* d_in, const int* in_sizes, int n_in,
                              void* d_out, int out_size, void* d_ws, size_t ws_size,
                              hipStream_t stream)
{
    const float* x   = (const float*)d_in[0];
    const float* dwk = (const float*)d_in[1];
    const float* dwb = (const float*)d_in[2];
    const float* g1  = (const float*)d_in[3];
    const float* b1  = (const float*)d_in[4];
    const float* m1  = (const float*)d_in[5];
    const float* v1  = (const float*)d_in[6];
    const float* pw  = (const float*)d_in[7];
    const float* pwb = (const float*)d_in[8];
    const float* g2  = (const float*)d_in[9];
    const float* b2  = (const float*)d_in[10];
    const float* m2  = (const float*)d_in[11];
    const float* v2  = (const float*)d_in[12];

    float* outp = (float*)d_out;

    float* scale1 = (float*)d_ws;
    float* shift1 = scale1 + 64;
    float* s2     = scale1 + 128;
    float* t2     = scale1 + 256;
    unsigned short* Wt = (unsigned short*)((char*)d_ws + 2048);

    hipLaunchKernelGGL(prep_kernel, dim3(32), dim3(256), 0, stream,
                       dwb, g1, b1, m1, v1, pw, pwb, g2, b2, m2, v2,
                       scale1, shift1, s2, t2, Wt);

    hipLaunchKernelGGL(fused_kernel, dim3(1152), dim3(256), 0, stream,
                       x, dwk, scale1, shift1, Wt, s2, t2, outp);
}